// Round 1
// baseline (165.790 us; speedup 1.0000x reference)
//
#include <hip/hip_runtime.h>

#define NB   4
#define NPIX 65536        // 256*256
#define ACCD 24
#define NC   576          // ACCD*ACCD
#define BIGV 1000000

struct Ws {
  int bin_min[NB * 2];
  int bin_max[NB * 2];
  unsigned acc[NB * NC];
  int table[NB * NC];
};

__global__ void k_init(Ws* ws) {
  int t = blockIdx.x * blockDim.x + threadIdx.x;
  if (t < NB * 2) { ws->bin_min[t] = BIGV; ws->bin_max[t] = -1; }
  for (int i = t; i < NB * NC; i += gridDim.x * blockDim.x) ws->acc[i] = 0u;
}

__device__ __forceinline__ void pixel_bins(const float* __restrict__ off, int b, int n,
                                           int& b0, int& b1) {
  const int y = n >> 8, x = n & 255;
  const float ox = off[(b * 2 + 0) * NPIX + n];
  const float oy = off[(b * 2 + 1) * NPIX + n];
  // votes / 16.0f  ==  votes * 0.0625f exactly (power of two)
  // rintf = round half to even, matching jnp.round
  b0 = (int)rintf(((float)x + ox) * 0.0625f);
  b1 = (int)rintf(((float)y + oy) * 0.0625f);
}

__global__ void __launch_bounds__(256) k_binmin(const float* __restrict__ off,
                                                const int* __restrict__ fg, Ws* ws) {
  const int b = blockIdx.x >> 8;
  const int n = ((blockIdx.x & 255) << 8) | threadIdx.x;
  int b0, b1;
  pixel_bins(off, b, n, b0, b1);
  const bool f = fg[b * NPIX + n] != 0;
  __shared__ int r0[256], r1[256];
  r0[threadIdx.x] = f ? b0 : BIGV;
  r1[threadIdx.x] = f ? b1 : BIGV;
  __syncthreads();
  for (int s = 128; s > 0; s >>= 1) {
    if (threadIdx.x < s) {
      r0[threadIdx.x] = min(r0[threadIdx.x], r0[threadIdx.x + s]);
      r1[threadIdx.x] = min(r1[threadIdx.x], r1[threadIdx.x + s]);
    }
    __syncthreads();
  }
  if (threadIdx.x == 0) {
    atomicMin(&ws->bin_min[b * 2 + 0], r0[0]);
    atomicMin(&ws->bin_min[b * 2 + 1], r1[0]);
  }
}

__global__ void __launch_bounds__(256) k_accum(const float* __restrict__ off,
                                               const int* __restrict__ fg, Ws* ws) {
  const int b = blockIdx.x >> 8;
  const int n = ((blockIdx.x & 255) << 8) | threadIdx.x;
  int b0, b1;
  pixel_bins(off, b, n, b0, b1);
  const int sh0 = b0 - ws->bin_min[b * 2 + 0];
  const int sh1 = b1 - ws->bin_min[b * 2 + 1];
  const bool f = fg[b * NPIX + n] != 0;
  if (f) {
    const int c0 = min(max(sh0, 0), ACCD - 1);
    const int c1 = min(max(sh1, 0), ACCD - 1);
    atomicAdd(&ws->acc[b * NC + c0 * ACCD + c1], 1u);
  }
  __shared__ int r0[256], r1[256];
  r0[threadIdx.x] = f ? sh0 : -1;
  r1[threadIdx.x] = f ? sh1 : -1;
  __syncthreads();
  for (int s = 128; s > 0; s >>= 1) {
    if (threadIdx.x < s) {
      r0[threadIdx.x] = max(r0[threadIdx.x], r0[threadIdx.x + s]);
      r1[threadIdx.x] = max(r1[threadIdx.x], r1[threadIdx.x + s]);
    }
    __syncthreads();
  }
  if (threadIdx.x == 0) {
    atomicMax(&ws->bin_max[b * 2 + 0], r0[0]);
    atomicMax(&ws->bin_max[b * 2 + 1], r1[0]);
  }
}

__global__ void __launch_bounds__(256) k_peaks(Ws* ws) {
  const int b = blockIdx.x;
  const int tid = threadIdx.x;
  __shared__ int cnt[NC];
  __shared__ float sm[NC];
  __shared__ int plist[NC];
  __shared__ float red[256];
  __shared__ int Psh;

  for (int c = tid; c < NC; c += 256) cnt[c] = (int)ws->acc[b * NC + c];
  __syncthreads();
  const int vm0 = ws->bin_max[b * 2 + 0] + 1;  // == reference bin_max
  const int vm1 = ws->bin_max[b * 2 + 1] + 1;

  float lmax = 0.f;
  for (int c = tid; c < NC; c += 256) {
    const int i = c / ACCD, j = c % ACCD;
    int sum = 0;
    const int i0 = max(i - 6, 0), i1 = min(i + 6, ACCD - 1);
    const int j0 = max(j - 6, 0), j1 = min(j + 6, ACCD - 1);
    for (int ii = i0; ii <= i1; ++ii)
      for (int jj = j0; jj <= j1; ++jj) sum += cnt[ii * ACCD + jj];
    float s = (float)sum * (1.0f / 169.0f);
    if (i >= vm0 || j >= vm1) s = 0.f;
    sm[c] = s;
    lmax = fmaxf(lmax, s);
  }
  red[tid] = lmax;
  __syncthreads();
  for (int s = 128; s > 0; s >>= 1) {
    if (tid < s) red[tid] = fmaxf(red[tid], red[tid + s]);
    __syncthreads();
  }
  const float thr = fmaxf(red[0] * 0.3f, 50.0f);

  if (tid == 0) {
    int p = 0;
    for (int c = 0; c < NC; ++c)
      if (sm[c] >= thr) plist[p++] = c;   // row-major order = argmin tie-break order
    Psh = p;
  }
  __syncthreads();
  const int P = Psh;

  for (int c = tid; c < NC; c += 256) {
    const int i = c / ACCD, j = c % ACCD;
    int best = 0x7fffffff, lab = 0;
    for (int k = 0; k < P; ++k) {
      const int pc = plist[k];
      const int pi = pc / ACCD, pj = pc % ACCD;
      const int di = i - pi, dj = j - pj;
      const int d = di * di + dj * dj;   // exact integer == f32 d2 of reference
      if (d < best) { best = d; lab = k + 1; }
    }
    ws->table[b * NC + c] = lab;
  }
}

__global__ void __launch_bounds__(256) k_label(const float* __restrict__ off,
                                               const int* __restrict__ fg,
                                               const Ws* __restrict__ ws,
                                               int* __restrict__ out) {
  const int b = blockIdx.x >> 8;
  const int n = ((blockIdx.x & 255) << 8) | threadIdx.x;
  int label = 0;
  if (fg[b * NPIX + n] != 0) {
    int b0, b1;
    pixel_bins(off, b, n, b0, b1);
    int s0 = b0 - ws->bin_min[b * 2 + 0];
    int s1 = b1 - ws->bin_min[b * 2 + 1];
    s0 = min(max(s0, 0), ACCD - 1);  // clamp = memory safety only; fg pixels are in range
    s1 = min(max(s1, 0), ACCD - 1);
    label = ws->table[b * NC + s0 * ACCD + s1];
  }
  out[b * NPIX + n] = label;
}

extern "C" void kernel_launch(void* const* d_in, const int* in_sizes, int n_in,
                              void* d_out, int out_size, void* d_ws, size_t ws_size,
                              hipStream_t stream) {
  const float* off = (const float*)d_in[0];
  const int* fg = (const int*)d_in[1];
  int* out = (int*)d_out;
  Ws* ws = (Ws*)d_ws;

  k_init<<<12, 256, 0, stream>>>(ws);
  k_binmin<<<1024, 256, 0, stream>>>(off, fg, ws);
  k_accum<<<1024, 256, 0, stream>>>(off, fg, ws);
  k_peaks<<<NB, 256, 0, stream>>>(ws);
  k_label<<<1024, 256, 0, stream>>>(off, fg, ws, out);
}

// Round 2
// 113.980 us; speedup vs baseline: 1.4545x; 1.4545x over previous
//
#include <hip/hip_runtime.h>

#define NB   4
#define NPIX 65536        // 256*256
#define ACCD 24
#define NC   576          // ACCD*ACCD
#define BIGV 1000000

struct Ws {
  int bin_min[NB * 2];   // raw bin mins (over fg)
  int bin_max[NB * 2];   // raw bin maxes (over fg)
  unsigned acc[NB * NC];
  int table[NB * NC];
};

__global__ void k_init(Ws* ws) {
  int t = blockIdx.x * blockDim.x + threadIdx.x;
  if (t < NB * 2) { ws->bin_min[t] = BIGV; ws->bin_max[t] = -BIGV; }
  for (int i = t; i < NB * NC; i += gridDim.x * blockDim.x) ws->acc[i] = 0u;
}

__device__ __forceinline__ void pixel_bins(const float* __restrict__ off, int b, int n,
                                           int& b0, int& b1) {
  const int y = n >> 8, x = n & 255;
  const float ox = off[(b * 2 + 0) * NPIX + n];
  const float oy = off[(b * 2 + 1) * NPIX + n];
  // /16 == *0.0625f exactly; rintf = round half to even, matching jnp.round
  b0 = (int)rintf(((float)x + ox) * 0.0625f);
  b1 = (int)rintf(((float)y + oy) * 0.0625f);
}

// pass 1: raw bin min AND max over foreground (shifted max = rawmax - rawmin)
__global__ void __launch_bounds__(256) k_binmm(const float* __restrict__ off,
                                               const int* __restrict__ fg, Ws* ws) {
  const int b = blockIdx.x >> 8;
  const int n = ((blockIdx.x & 255) << 8) | threadIdx.x;
  int b0, b1;
  pixel_bins(off, b, n, b0, b1);
  const bool f = fg[b * NPIX + n] != 0;
  int mn0 = f ? b0 : BIGV, mn1 = f ? b1 : BIGV;
  int mx0 = f ? b0 : -BIGV, mx1 = f ? b1 : -BIGV;
  for (int o = 32; o > 0; o >>= 1) {
    mn0 = min(mn0, __shfl_xor(mn0, o, 64));
    mn1 = min(mn1, __shfl_xor(mn1, o, 64));
    mx0 = max(mx0, __shfl_xor(mx0, o, 64));
    mx1 = max(mx1, __shfl_xor(mx1, o, 64));
  }
  __shared__ int s[4][4];
  const int lane = threadIdx.x & 63, wid = threadIdx.x >> 6;
  if (lane == 0) { s[wid][0] = mn0; s[wid][1] = mn1; s[wid][2] = mx0; s[wid][3] = mx1; }
  __syncthreads();
  if (threadIdx.x == 0) {
    int a0 = s[0][0], a1 = s[0][1], c0 = s[0][2], c1 = s[0][3];
    for (int w = 1; w < 4; ++w) {
      a0 = min(a0, s[w][0]); a1 = min(a1, s[w][1]);
      c0 = max(c0, s[w][2]); c1 = max(c1, s[w][3]);
    }
    atomicMin(&ws->bin_min[b * 2 + 0], a0);
    atomicMin(&ws->bin_min[b * 2 + 1], a1);
    atomicMax(&ws->bin_max[b * 2 + 0], c0);
    atomicMax(&ws->bin_max[b * 2 + 1], c1);
  }
}

// pass 2: scatter-add votes (shift by global raw min)
__global__ void __launch_bounds__(256) k_accum(const float* __restrict__ off,
                                               const int* __restrict__ fg, Ws* ws) {
  const int b = blockIdx.x >> 8;
  const int n = ((blockIdx.x & 255) << 8) | threadIdx.x;
  if (fg[b * NPIX + n] != 0) {
    int b0, b1;
    pixel_bins(off, b, n, b0, b1);
    const int c0 = min(max(b0 - ws->bin_min[b * 2 + 0], 0), ACCD - 1);
    const int c1 = min(max(b1 - ws->bin_min[b * 2 + 1], 0), ACCD - 1);
    atomicAdd(&ws->acc[b * NC + c0 * ACCD + c1], 1u);
  }
}

// pass 3: smooth + threshold + peak compaction + nearest-peak label table.
// 576 threads = one per accumulator cell; fully parallel, no serial LDS chains.
__global__ void __launch_bounds__(576) k_peaks(Ws* ws) {
  const int b = blockIdx.x;
  const int c = threadIdx.x;            // 0..575
  const int i = c / ACCD, j = c % ACCD;
  const int lane = c & 63, wid = c >> 6;  // 9 waves

  __shared__ int cnt[NC];
  __shared__ int rowsum[NC];
  __shared__ int plist[NC];             // packed (pi<<8)|pj, row-major rank order
  __shared__ float wmax[9];
  __shared__ int wcnt[9];
  __shared__ int woff[10];
  __shared__ float thrsh;
  __shared__ int Psh;

  cnt[c] = (int)ws->acc[b * NC + c];
  __syncthreads();

  // separable 13x13 box sum (zero padding == clamped window over zero-beyond cells)
  {
    int s = 0;
    const int j0 = max(j - 6, 0), j1 = min(j + 6, ACCD - 1);
    for (int jj = j0; jj <= j1; ++jj) s += cnt[i * ACCD + jj];
    rowsum[c] = s;
  }
  __syncthreads();
  int sum = 0;
  {
    const int i0 = max(i - 6, 0), i1 = min(i + 6, ACCD - 1);
    for (int ii = i0; ii <= i1; ++ii) sum += rowsum[ii * ACCD + j];
  }
  float sm = (float)sum * (1.0f / 169.0f);
  const int vm0 = ws->bin_max[b * 2 + 0] - ws->bin_min[b * 2 + 0] + 1;
  const int vm1 = ws->bin_max[b * 2 + 1] - ws->bin_min[b * 2 + 1] + 1;
  if (i >= vm0 || j >= vm1) sm = 0.f;

  // block max via wave shuffles
  float m = sm;
  for (int o = 32; o > 0; o >>= 1) m = fmaxf(m, __shfl_xor(m, o, 64));
  if (lane == 0) wmax[wid] = m;
  __syncthreads();
  if (c == 0) {
    float mm = wmax[0];
    for (int w = 1; w < 9; ++w) mm = fmaxf(mm, wmax[w]);
    thrsh = fmaxf(mm * 0.3f, 50.0f);
  }
  __syncthreads();

  // parallel peak compaction in row-major order (ballot + prefix)
  const bool flag = sm >= thrsh;
  const unsigned long long mask = __ballot(flag);
  const int rank = (int)__popcll(mask & ((1ull << lane) - 1ull));
  if (lane == 0) wcnt[wid] = (int)__popcll(mask);
  __syncthreads();
  if (c == 0) {
    woff[0] = 0;
    for (int w = 0; w < 9; ++w) woff[w + 1] = woff[w] + wcnt[w];
    Psh = woff[9];
  }
  __syncthreads();
  if (flag) plist[woff[wid] + rank] = (i << 8) | j;
  __syncthreads();

  // nearest peak: argmin with first-occurrence tie-break == min of key (d<<10)|k
  // (d = exact integer squared distance, == the reference's f32 d2 exactly)
  const int P = Psh;
  int bestkey = 0x7fffffff;
  int k = 0;
  for (; k + 7 < P; k += 8) {
#pragma unroll
    for (int u = 0; u < 8; ++u) {
      const int pk = plist[k + u];
      const int di = i - (pk >> 8), dj = j - (pk & 255);
      const int key = ((di * di + dj * dj) << 10) | (k + u);
      bestkey = min(bestkey, key);
    }
  }
  for (; k < P; ++k) {
    const int pk = plist[k];
    const int di = i - (pk >> 8), dj = j - (pk & 255);
    const int key = ((di * di + dj * dj) << 10) | k;
    bestkey = min(bestkey, key);
  }
  ws->table[b * NC + c] = (P > 0) ? ((bestkey & 1023) + 1) : 0;
}

// pass 4: per-pixel label lookup
__global__ void __launch_bounds__(256) k_label(const float* __restrict__ off,
                                               const int* __restrict__ fg,
                                               const Ws* __restrict__ ws,
                                               int* __restrict__ out) {
  const int b = blockIdx.x >> 8;
  const int n = ((blockIdx.x & 255) << 8) | threadIdx.x;
  int label = 0;
  if (fg[b * NPIX + n] != 0) {
    int b0, b1;
    pixel_bins(off, b, n, b0, b1);
    const int s0 = min(max(b0 - ws->bin_min[b * 2 + 0], 0), ACCD - 1);
    const int s1 = min(max(b1 - ws->bin_min[b * 2 + 1], 0), ACCD - 1);
    label = ws->table[b * NC + s0 * ACCD + s1];
  }
  out[b * NPIX + n] = label;
}

extern "C" void kernel_launch(void* const* d_in, const int* in_sizes, int n_in,
                              void* d_out, int out_size, void* d_ws, size_t ws_size,
                              hipStream_t stream) {
  const float* off = (const float*)d_in[0];
  const int* fg = (const int*)d_in[1];
  int* out = (int*)d_out;
  Ws* ws = (Ws*)d_ws;

  k_init<<<12, 256, 0, stream>>>(ws);
  k_binmm<<<1024, 256, 0, stream>>>(off, fg, ws);
  k_accum<<<1024, 256, 0, stream>>>(off, fg, ws);
  k_peaks<<<NB, 576, 0, stream>>>(ws);
  k_label<<<1024, 256, 0, stream>>>(off, fg, ws, out);
}

// Round 3
// 29.476 us; speedup vs baseline: 5.6245x; 3.8669x over previous
//
#include <hip/hip_runtime.h>

#define NB   4
#define NPIX 65536        // 256*256
#define ACCD 24
#define NC   576          // ACCD*ACCD
#define BIGV 1000000

struct Ws {
  int bin_min[NB * 2];   // raw bin mins (over fg)   [written by plain store]
  int bin_max[NB * 2];   // raw bin maxes (over fg)
  int4 part[256];        // per-block partials {mn0,mn1,mx0,mx1}
  unsigned acc[NB * NC];
  int table[NB * NC];
};

__device__ __forceinline__ int2 bin_of(float ox, float oy, int x, int y) {
  // /16 == *0.0625f exactly; rintf = round half to even, matching jnp.round
  return make_int2((int)rintf(((float)x + ox) * 0.0625f),
                   (int)rintf(((float)y + oy) * 0.0625f));
}

// pass 1: per-block raw bin min/max over foreground -> distinct slots (NO atomics)
// 256 blocks (64/batch), 256 threads, 4 px/thread vectorized.
__global__ void __launch_bounds__(256) k_binmm(const float* __restrict__ off,
                                               const int* __restrict__ fg, Ws* ws) {
  const int b = blockIdx.x >> 6;
  const int n0 = ((blockIdx.x & 63) << 10) | (threadIdx.x << 2);  // 4 consecutive px
  const float4 ox4 = *(const float4*)&off[(b * 2 + 0) * NPIX + n0];
  const float4 oy4 = *(const float4*)&off[(b * 2 + 1) * NPIX + n0];
  const int4 fg4 = *(const int4*)&fg[b * NPIX + n0];

  int mn0 = BIGV, mn1 = BIGV, mx0 = -BIGV, mx1 = -BIGV;
  const float oxs[4] = {ox4.x, ox4.y, ox4.z, ox4.w};
  const float oys[4] = {oy4.x, oy4.y, oy4.z, oy4.w};
  const int fgs[4] = {fg4.x, fg4.y, fg4.z, fg4.w};
#pragma unroll
  for (int u = 0; u < 4; ++u) {
    const int n = n0 + u;
    const int2 bb = bin_of(oxs[u], oys[u], n & 255, n >> 8);
    if (fgs[u] != 0) {
      mn0 = min(mn0, bb.x); mn1 = min(mn1, bb.y);
      mx0 = max(mx0, bb.x); mx1 = max(mx1, bb.y);
    }
  }
  for (int o = 32; o > 0; o >>= 1) {
    mn0 = min(mn0, __shfl_xor(mn0, o, 64));
    mn1 = min(mn1, __shfl_xor(mn1, o, 64));
    mx0 = max(mx0, __shfl_xor(mx0, o, 64));
    mx1 = max(mx1, __shfl_xor(mx1, o, 64));
  }
  __shared__ int s[4][4];
  const int lane = threadIdx.x & 63, wid = threadIdx.x >> 6;
  if (lane == 0) { s[wid][0] = mn0; s[wid][1] = mn1; s[wid][2] = mx0; s[wid][3] = mx1; }
  __syncthreads();
  if (threadIdx.x == 0) {
    int a0 = s[0][0], a1 = s[0][1], c0 = s[0][2], c1 = s[0][3];
    for (int w = 1; w < 4; ++w) {
      a0 = min(a0, s[w][0]); a1 = min(a1, s[w][1]);
      c0 = max(c0, s[w][2]); c1 = max(c1, s[w][3]);
    }
    ws->part[blockIdx.x] = make_int4(a0, a1, c0, c1);
  }
}

// pass 2: reduce 64 partials/batch -> bin_min/bin_max (plain stores); zero acc.
__global__ void __launch_bounds__(576) k_minred(Ws* ws) {
  const int b = blockIdx.x;
  const int t = threadIdx.x;
  if (t < 64) {
    const int4 p = ws->part[b * 64 + t];
    int mn0 = p.x, mn1 = p.y, mx0 = p.z, mx1 = p.w;
    for (int o = 32; o > 0; o >>= 1) {
      mn0 = min(mn0, __shfl_xor(mn0, o, 64));
      mn1 = min(mn1, __shfl_xor(mn1, o, 64));
      mx0 = max(mx0, __shfl_xor(mx0, o, 64));
      mx1 = max(mx1, __shfl_xor(mx1, o, 64));
    }
    if (t == 0) {
      ws->bin_min[b * 2 + 0] = mn0; ws->bin_min[b * 2 + 1] = mn1;
      ws->bin_max[b * 2 + 0] = mx0; ws->bin_max[b * 2 + 1] = mx1;
    }
  }
  ws->acc[b * NC + t] = 0u;   // blockDim == NC
}

// pass 3: scatter-add votes via LDS histogram, then few global atomics.
// 64 blocks (16/batch), 1024 threads, 4 px/thread.
__global__ void __launch_bounds__(1024) k_accum(const float* __restrict__ off,
                                                const int* __restrict__ fg, Ws* ws) {
  const int b = blockIdx.x >> 4;
  const int n0 = ((blockIdx.x & 15) << 12) | (threadIdx.x << 2);
  __shared__ unsigned h[NC];
  if (threadIdx.x < NC) h[threadIdx.x] = 0u;
  __syncthreads();

  const int m0 = ws->bin_min[b * 2 + 0], m1 = ws->bin_min[b * 2 + 1];
  const float4 ox4 = *(const float4*)&off[(b * 2 + 0) * NPIX + n0];
  const float4 oy4 = *(const float4*)&off[(b * 2 + 1) * NPIX + n0];
  const int4 fg4 = *(const int4*)&fg[b * NPIX + n0];
  const float oxs[4] = {ox4.x, ox4.y, ox4.z, ox4.w};
  const float oys[4] = {oy4.x, oy4.y, oy4.z, oy4.w};
  const int fgs[4] = {fg4.x, fg4.y, fg4.z, fg4.w};
#pragma unroll
  for (int u = 0; u < 4; ++u) {
    if (fgs[u] != 0) {
      const int n = n0 + u;
      const int2 bb = bin_of(oxs[u], oys[u], n & 255, n >> 8);
      const int c0 = min(max(bb.x - m0, 0), ACCD - 1);
      const int c1 = min(max(bb.y - m1, 0), ACCD - 1);
      atomicAdd(&h[c0 * ACCD + c1], 1u);
    }
  }
  __syncthreads();
  if (threadIdx.x < NC) {
    const unsigned v = h[threadIdx.x];
    if (v) atomicAdd(&ws->acc[b * NC + threadIdx.x], v);
  }
}

// pass 4: smooth + threshold + peak compaction + nearest-peak label table.
__global__ void __launch_bounds__(576) k_peaks(Ws* ws) {
  const int b = blockIdx.x;
  const int c = threadIdx.x;            // 0..575
  const int i = c / ACCD, j = c % ACCD;
  const int lane = c & 63, wid = c >> 6;  // 9 waves

  __shared__ int cnt[NC];
  __shared__ int rowsum[NC];
  __shared__ int plist[NC];
  __shared__ float wmax[9];
  __shared__ int wcnt[9];
  __shared__ int woff[10];
  __shared__ float thrsh;
  __shared__ int Psh;

  cnt[c] = (int)ws->acc[b * NC + c];
  __syncthreads();

  {
    int s = 0;
    const int j0 = max(j - 6, 0), j1 = min(j + 6, ACCD - 1);
    for (int jj = j0; jj <= j1; ++jj) s += cnt[i * ACCD + jj];
    rowsum[c] = s;
  }
  __syncthreads();
  int sum = 0;
  {
    const int i0 = max(i - 6, 0), i1 = min(i + 6, ACCD - 1);
    for (int ii = i0; ii <= i1; ++ii) sum += rowsum[ii * ACCD + j];
  }
  float sm = (float)sum * (1.0f / 169.0f);
  const int vm0 = ws->bin_max[b * 2 + 0] - ws->bin_min[b * 2 + 0] + 1;
  const int vm1 = ws->bin_max[b * 2 + 1] - ws->bin_min[b * 2 + 1] + 1;
  if (i >= vm0 || j >= vm1) sm = 0.f;

  float m = sm;
  for (int o = 32; o > 0; o >>= 1) m = fmaxf(m, __shfl_xor(m, o, 64));
  if (lane == 0) wmax[wid] = m;
  __syncthreads();
  if (c == 0) {
    float mm = wmax[0];
    for (int w = 1; w < 9; ++w) mm = fmaxf(mm, wmax[w]);
    thrsh = fmaxf(mm * 0.3f, 50.0f);
  }
  __syncthreads();

  const bool flag = sm >= thrsh;
  const unsigned long long mask = __ballot(flag);
  const int rank = (int)__popcll(mask & ((1ull << lane) - 1ull));
  if (lane == 0) wcnt[wid] = (int)__popcll(mask);
  __syncthreads();
  if (c == 0) {
    woff[0] = 0;
    for (int w = 0; w < 9; ++w) woff[w + 1] = woff[w] + wcnt[w];
    Psh = woff[9];
  }
  __syncthreads();
  if (flag) plist[woff[wid] + rank] = (i << 8) | j;
  __syncthreads();

  // argmin w/ first-occurrence tie-break == min of key (d<<10)|k; d exact int
  const int P = Psh;
  int bestkey = 0x7fffffff;
  int k = 0;
  for (; k + 7 < P; k += 8) {
#pragma unroll
    for (int u = 0; u < 8; ++u) {
      const int pk = plist[k + u];
      const int di = i - (pk >> 8), dj = j - (pk & 255);
      const int key = ((di * di + dj * dj) << 10) | (k + u);
      bestkey = min(bestkey, key);
    }
  }
  for (; k < P; ++k) {
    const int pk = plist[k];
    const int di = i - (pk >> 8), dj = j - (pk & 255);
    const int key = ((di * di + dj * dj) << 10) | k;
    bestkey = min(bestkey, key);
  }
  ws->table[b * NC + c] = (P > 0) ? ((bestkey & 1023) + 1) : 0;
}

// pass 5: per-pixel label lookup, 4 px/thread, table staged in LDS.
__global__ void __launch_bounds__(256) k_label(const float* __restrict__ off,
                                               const int* __restrict__ fg,
                                               const Ws* __restrict__ ws,
                                               int* __restrict__ out) {
  const int b = blockIdx.x >> 6;
  const int n0 = ((blockIdx.x & 63) << 10) | (threadIdx.x << 2);
  __shared__ int tbl[NC];
  for (int t = threadIdx.x; t < NC; t += 256) tbl[t] = ws->table[b * NC + t];
  __syncthreads();

  const int m0 = ws->bin_min[b * 2 + 0], m1 = ws->bin_min[b * 2 + 1];
  const float4 ox4 = *(const float4*)&off[(b * 2 + 0) * NPIX + n0];
  const float4 oy4 = *(const float4*)&off[(b * 2 + 1) * NPIX + n0];
  const int4 fg4 = *(const int4*)&fg[b * NPIX + n0];
  const float oxs[4] = {ox4.x, ox4.y, ox4.z, ox4.w};
  const float oys[4] = {oy4.x, oy4.y, oy4.z, oy4.w};
  const int fgs[4] = {fg4.x, fg4.y, fg4.z, fg4.w};
  int lab[4];
#pragma unroll
  for (int u = 0; u < 4; ++u) {
    lab[u] = 0;
    if (fgs[u] != 0) {
      const int n = n0 + u;
      const int2 bb = bin_of(oxs[u], oys[u], n & 255, n >> 8);
      const int s0 = min(max(bb.x - m0, 0), ACCD - 1);
      const int s1 = min(max(bb.y - m1, 0), ACCD - 1);
      lab[u] = tbl[s0 * ACCD + s1];
    }
  }
  *(int4*)&out[b * NPIX + n0] = make_int4(lab[0], lab[1], lab[2], lab[3]);
}

extern "C" void kernel_launch(void* const* d_in, const int* in_sizes, int n_in,
                              void* d_out, int out_size, void* d_ws, size_t ws_size,
                              hipStream_t stream) {
  const float* off = (const float*)d_in[0];
  const int* fg = (const int*)d_in[1];
  int* out = (int*)d_out;
  Ws* ws = (Ws*)d_ws;

  k_binmm<<<256, 256, 0, stream>>>(off, fg, ws);
  k_minred<<<NB, 576, 0, stream>>>(ws);
  k_accum<<<64, 1024, 0, stream>>>(off, fg, ws);
  k_peaks<<<NB, 576, 0, stream>>>(ws);
  k_label<<<256, 256, 0, stream>>>(off, fg, ws, out);
}